// Round 5
// baseline (158.480 us; speedup 1.0000x reference)
//
#include <hip/hip_runtime.h>

// MGN_NET: 3x NNConv(mean) + ReLU, then pairwise-L1 CBT [35x35]. All fp32.
// 2 dispatches: init (zero barrier counters) + mega-kernel (476 blocks x 512)
// with 4 software grid barriers + one 35-way flag.
// R4 -> R5: grid 238 -> 476 blocks (2 blocks/CU, 16 waves/CU) to hide
// weight-stream latency; PB split by o-half (atomic count unchanged);
// PD split by o-half; agg replica picked by eg&3 (true 4-way spread);
// barrier arrivals over 16 distinct cache lines.
// Coherence: cross-block data via agent-scope relaxed atomics (sc1 -> LLC);
// aggregation via device atomicAdd (LLC-coherent). Barriers fence-free:
// __syncthreads() drains vmcnt, so sc1 stores are at LLC before arrival.
// Safety: __launch_bounds__(512,4) => VGPR<=128 => >=2 blocks/CU co-resident
// capacity = 512 >= 476 => grid-wide spin barrier cannot deadlock.

#define NN 35
#define NE 1190
#define NBLK 476
#define TE2 10
#define TE3 5
#define MAXE 96

// float offsets into ws (u32 bar region [0,320): 16 lines + flag@256)
#define OFF_CNT  320     // 35
#define OFF_X1   384     // 8960 -> 9344
#define OFF_X2   9344    // 8960 -> 18304
#define OFF_X3   18304   // 2240 -> 20544
#define OFF_AGG2 20608   // 4*8960 = 35840 -> 56448
#define OFF_AGG3 56448   // 4*2240 = 8960  -> 65408 (contiguous with AGG2)
#define NZERO2   22400   // (35840+8960)/2 float2 zero-stores

__global__ __launch_bounds__(64) void init_k(unsigned* bar) {
    for (int i = threadIdx.x; i < 320; i += 64) bar[i] = 0u;
}

// Agent-scope (LLC-coherent, sc1) relaxed accessors.
__device__ __forceinline__ float ld_c(const float* p) {
    return __hip_atomic_load(p, __ATOMIC_RELAXED, __HIP_MEMORY_SCOPE_AGENT);
}
__device__ __forceinline__ void st_c(float* p, float v) {
    __hip_atomic_store(p, v, __ATOMIC_RELAXED, __HIP_MEMORY_SCOPE_AGENT);
}
__device__ __forceinline__ float2 ld_c2(const float* p) {
    union { double d; float2 f; } u;
    u.d = __hip_atomic_load((const double*)p, __ATOMIC_RELAXED,
                            __HIP_MEMORY_SCOPE_AGENT);
    return u.f;
}
__device__ __forceinline__ void st_c2(float* p, float2 v) {
    union { double d; float2 f; } u;
    u.f = v;
    __hip_atomic_store((double*)p, u.d, __ATOMIC_RELAXED,
                       __HIP_MEMORY_SCOPE_AGENT);
}

// Grid barrier: 16 counters on 16 DISTINCT 64B lines (bar[i*16]).
// Sum-poll correctness by induction on rounds.
__device__ __forceinline__ void gbar(unsigned* bar, unsigned target) {
    __syncthreads();
    if (threadIdx.x == 0) {
        __hip_atomic_fetch_add(bar + (blockIdx.x & 15) * 16, 1u,
                               __ATOMIC_RELAXED, __HIP_MEMORY_SCOPE_AGENT);
        for (;;) {
            unsigned s = 0;
#pragma unroll
            for (int i = 0; i < 16; i++)
                s += __hip_atomic_load(bar + i * 16, __ATOMIC_RELAXED,
                                       __HIP_MEMORY_SCOPE_AGENT);
            if (s >= target) break;
            __builtin_amdgcn_s_sleep(8);
        }
        asm volatile("" ::: "memory");
    }
    __syncthreads();
}

__global__ __launch_bounds__(512, 4) void mega_k(
    float* __restrict__ ws, const float* __restrict__ x,
    const float* __restrict__ ea, const int* __restrict__ ei,
    const float* __restrict__ w1, const float* __restrict__ b1w,
    const float* __restrict__ lin1, const float* __restrict__ b1,
    const float* __restrict__ w2, const float* __restrict__ b2w,
    const float* __restrict__ lin2, const float* __restrict__ b2,
    const float* __restrict__ w3, const float* __restrict__ b3w,
    const float* __restrict__ lin3, const float* __restrict__ b3,
    float* __restrict__ out) {
    __shared__ float smem[5376];  // 21.5 KiB, re-purposed per phase
    unsigned* bar = (unsigned*)ws;
    const int tid = threadIdx.x;
    const int bid = blockIdx.x;

    // ---------------- PA: x1 slices (140 blk) + zero agg replicas ----------
    if (bid < 140) {
        const int n = bid >> 2, och = bid & 3;
        int* elistS = (int*)smem;            // 96
        int* ecntS = (int*)smem + 96;        // 1
        float* partS = smem + 128;           // 8*64
        if (tid == 0) *ecntS = 0;
        __syncthreads();
        for (int e = tid; e < NE; e += 512) {
            if (ei[NE + e] == n) {
                const int p = atomicAdd(ecntS, 1);
                if (p < MAXE) elistS[p] = e;
            }
        }
        __syncthreads();
        const int deg = *ecntS;
        const int dl = deg < MAXE ? deg : MAXE;
        const int ol = tid & 63, ech = tid >> 6;
        const int o = och * 64 + ol;
        const float2* wr = (const float2*)(w1 + o * 6);
        const float2 wv0 = wr[0], wv1 = wr[1], wv2 = wr[2];
        const float bb = b1w[o];
        float a = 0.f;
        for (int k = ech; k < dl; k += 8) {
            const int e = elistS[k];
            const float2* eap = (const float2*)(ea + e * 6);
            const float2 a0 = eap[0], a1 = eap[1], a2 = eap[2];
            float d = bb;
            d = fmaf(a0.x, wv0.x, d); d = fmaf(a0.y, wv0.y, d);
            d = fmaf(a1.x, wv1.x, d); d = fmaf(a1.y, wv1.y, d);
            d = fmaf(a2.x, wv2.x, d); d = fmaf(a2.y, wv2.y, d);
            a = fmaf(x[ei[e]], fmaxf(d, 0.f), a);
        }
        partS[ech * 64 + ol] = a;
        __syncthreads();
        if (ech == 0) {
            float s = a;
#pragma unroll
            for (int p = 1; p < 8; p++) s += partS[p * 64 + ol];
            const float c = fmaxf((float)deg, 1.f);
            st_c(ws + OFF_X1 + n * 256 + o,
                 fmaxf(s / c + x[n] * lin1[o] + b1[o], 0.f));
        }
        if (och == 0 && tid == 0) st_c(ws + OFF_CNT + n, (float)deg);
    } else if (bid < 184) {
        // zero 4x agg2 + 4x agg3 replicas (contiguous 44800 floats)
        const int idx = (bid - 140) * 512 + tid;
        if (idx < NZERO2) {
            float2 z; z.x = 0.f; z.y = 0.f;
            st_c2(ws + OFF_AGG2 + idx * 2, z);
        }
    }
    gbar(bar, NBLK * 1u);

    // ------- PB: layer-2 edge msgs (i-half x o-half) -> agg2 replica -------
    {
        const int eg = bid >> 2, sub = bid & 3;
        const int ig = sub >> 1, og = sub & 1;
        const int e0 = eg * TE2;
        const int rep = eg & 3;
        int* srcsS = (int*)smem;         // 10
        int* dstsS = (int*)smem + 16;    // 10
        float* easS = smem + 32;         // 60 -> ends 92
        float* xsS = smem + 96;          // 10*128 -> ends 1376
        float* partS = smem + 1408;      // 3*10*128 -> ends 5248
        if (tid < TE2) { srcsS[tid] = ei[e0 + tid]; dstsS[tid] = ei[NE + e0 + tid]; }
        if (tid >= 64 && tid < 64 + TE2 * 6) {
            const int t = tid - 64;
            easS[t] = ea[e0 * 6 + t];
        }
        __syncthreads();
        for (int idx = tid; idx < TE2 * 64; idx += 512) {
            const int te = idx >> 6, ip = (idx & 63) * 2;
            *(float2*)&xsS[te * 128 + ip] =
                ld_c2(ws + OFF_X1 + srcsS[te] * 256 + ig * 128 + ip);
        }
        __syncthreads();
        const int ol = tid & 127, ich = tid >> 7;  // 4 chunks of 32 i
        const int o = og * 128 + ol;
        float ear[TE2][6];
#pragma unroll
        for (int te = 0; te < TE2; te++)
#pragma unroll
            for (int v = 0; v < 6; v++) ear[te][v] = easS[te * 6 + v];
        float acc[TE2] = {};
        for (int ii = 0; ii < 32; ii++) {
            const int il = ich * 32 + ii;    // i within the 128-half
            const int i = ig * 128 + il;
            const float* wp = w2 + (size_t)(i * 256 + o) * 6;
            const float2 wa = *(const float2*)wp;
            const float2 wb = *(const float2*)(wp + 2);
            const float2 wc = *(const float2*)(wp + 4);
            const float b = b2w[i * 256 + o];
#pragma unroll
            for (int te = 0; te < TE2; te += 2) {
                float dx = b, dy = b;
                dx = fmaf(ear[te][0], wa.x, dx); dy = fmaf(ear[te+1][0], wa.x, dy);
                dx = fmaf(ear[te][1], wa.y, dx); dy = fmaf(ear[te+1][1], wa.y, dy);
                dx = fmaf(ear[te][2], wb.x, dx); dy = fmaf(ear[te+1][2], wb.x, dy);
                dx = fmaf(ear[te][3], wb.y, dx); dy = fmaf(ear[te+1][3], wb.y, dy);
                dx = fmaf(ear[te][4], wc.x, dx); dy = fmaf(ear[te+1][4], wc.x, dy);
                dx = fmaf(ear[te][5], wc.y, dx); dy = fmaf(ear[te+1][5], wc.y, dy);
                dx = fmaxf(dx, 0.f);             dy = fmaxf(dy, 0.f);
                acc[te]   = fmaf(xsS[te * 128 + il], dx, acc[te]);
                acc[te+1] = fmaf(xsS[(te+1) * 128 + il], dy, acc[te+1]);
            }
        }
        if (ich > 0) {
#pragma unroll
            for (int te = 0; te < TE2; te++)
                partS[(ich - 1) * 1280 + te * 128 + ol] = acc[te];
        }
        __syncthreads();
        if (ich == 0) {
#pragma unroll
            for (int te = 0; te < TE2; te++) {
                float s = acc[te] + partS[te * 128 + ol]
                        + partS[1280 + te * 128 + ol]
                        + partS[2560 + te * 128 + ol];
                atomicAdd(ws + OFF_AGG2 + rep * 8960 + dstsS[te] * 256 + o, s);
            }
        }
    }
    gbar(bar, NBLK * 2u);

    // ---------------- PC: x2 = relu(sum(agg2 reps)/c + lin2.x1 + b2) -------
    if (bid < 140) {
        const int n = bid >> 2, og = bid & 3;
        float* x1S = smem;               // 256
        float* partS = smem + 256;       // 8*64
        float* cS = smem + 768;          // 1
        if (tid == 0) cS[0] = ld_c(ws + OFF_CNT + n);
        if (tid >= 128 && tid < 256) {
            const int ip = (tid - 128) * 2;
            *(float2*)&x1S[ip] = ld_c2(ws + OFF_X1 + n * 256 + ip);
        }
        __syncthreads();
        const int ol = tid & 63, ic = tid >> 6;
        const int o = og * 64 + ol;
        const float4* l4 = (const float4*)(lin2 + (size_t)o * 256 + ic * 32);
        const float* xs = x1S + ic * 32;
        float s = 0.f;
#pragma unroll
        for (int k = 0; k < 8; k++) {
            const float4 wv = l4[k];
            s = fmaf(wv.x, xs[k * 4], s);
            s = fmaf(wv.y, xs[k * 4 + 1], s);
            s = fmaf(wv.z, xs[k * 4 + 2], s);
            s = fmaf(wv.w, xs[k * 4 + 3], s);
        }
        partS[ic * 64 + ol] = s;
        __syncthreads();
        if (ic == 0) {
            float t = s;
#pragma unroll
            for (int p = 1; p < 8; p++) t += partS[p * 64 + ol];
            float g = 0.f;
#pragma unroll
            for (int r = 0; r < 4; r++)
                g += ld_c(ws + OFF_AGG2 + r * 8960 + n * 256 + o);
            const float c = fmaxf(cS[0], 1.f);
            st_c(ws + OFF_X2 + n * 256 + o, fmaxf(g / c + t + b2[o], 0.f));
        }
    }
    gbar(bar, NBLK * 3u);

    // ------- PD: layer-3 edge msgs (o-half) -> agg3 replica ----------------
    {
        const int eg = bid >> 1, oh = bid & 1;
        const int e0 = eg * TE3;
        const int rep = eg & 3;
        int* srcsS = (int*)smem;         // 5
        int* dstsS = (int*)smem + 8;     // 5
        float* easS = smem + 16;         // 30 -> 46
        float* xsS = smem + 64;          // 5*256 -> ends 1344
        float* partS = smem + 1344;      // 15*5*32 = 2400 -> ends 3744
        if (tid < TE3) { srcsS[tid] = ei[e0 + tid]; dstsS[tid] = ei[NE + e0 + tid]; }
        if (tid >= 64 && tid < 64 + TE3 * 6) {
            const int t = tid - 64;
            easS[t] = ea[e0 * 6 + t];
        }
        __syncthreads();
        for (int idx = tid; idx < TE3 * 128; idx += 512) {
            const int te = idx >> 7, ip = (idx & 127) * 2;
            *(float2*)&xsS[te * 256 + ip] =
                ld_c2(ws + OFF_X2 + srcsS[te] * 256 + ip);
        }
        __syncthreads();
        const int o3l = tid & 31, ic = tid >> 5;  // 16 chunks of 16 i
        const int o3 = oh * 32 + o3l;
        float ear[TE3][6];
#pragma unroll
        for (int te = 0; te < TE3; te++)
#pragma unroll
            for (int v = 0; v < 6; v++) ear[te][v] = easS[te * 6 + v];
        float acc[TE3] = {};
        for (int ii = 0; ii < 16; ii++) {
            const int i = ic * 16 + ii;
            const float* wp = w3 + (size_t)(i * 64 + o3) * 6;
            const float2 wa = *(const float2*)wp;
            const float2 wb = *(const float2*)(wp + 2);
            const float2 wc = *(const float2*)(wp + 4);
            const float b = b3w[i * 64 + o3];
#pragma unroll
            for (int te = 0; te < TE3; te++) {
                float d = b;
                d = fmaf(ear[te][0], wa.x, d);
                d = fmaf(ear[te][1], wa.y, d);
                d = fmaf(ear[te][2], wb.x, d);
                d = fmaf(ear[te][3], wb.y, d);
                d = fmaf(ear[te][4], wc.x, d);
                d = fmaf(ear[te][5], wc.y, d);
                acc[te] = fmaf(xsS[te * 256 + i], fmaxf(d, 0.f), acc[te]);
            }
        }
        if (ic > 0) {
#pragma unroll
            for (int te = 0; te < TE3; te++)
                partS[(ic - 1) * 160 + te * 32 + o3l] = acc[te];
        }
        __syncthreads();
        if (ic == 0) {
#pragma unroll
            for (int te = 0; te < TE3; te++) {
                float s = acc[te];
#pragma unroll
                for (int p = 0; p < 15; p++) s += partS[p * 160 + te * 32 + o3l];
                atomicAdd(ws + OFF_AGG3 + rep * 2240 + dstsS[te] * 64 + o3, s);
            }
        }
    }
    gbar(bar, NBLK * 4u);

    // ---------------- PE: x3 (own node) + 35-flag + CBT --------------------
    if (bid >= NN) return;
    {
        const int n = bid;
        float* x2S = smem;               // 256
        float* partS = smem + 256;       // 8*64
        float* cS = smem + 768;          // 1
        if (tid == 0) cS[0] = ld_c(ws + OFF_CNT + n);
        if (tid >= 128 && tid < 256) {
            const int ip = (tid - 128) * 2;
            *(float2*)&x2S[ip] = ld_c2(ws + OFF_X2 + n * 256 + ip);
        }
        __syncthreads();
        const int o3 = tid & 63, ic = tid >> 6;
        const float4* l4 = (const float4*)(lin3 + (size_t)o3 * 256 + ic * 32);
        const float* xs = x2S + ic * 32;
        float s = 0.f;
#pragma unroll
        for (int k = 0; k < 8; k++) {
            const float4 wv = l4[k];
            s = fmaf(wv.x, xs[k * 4], s);
            s = fmaf(wv.y, xs[k * 4 + 1], s);
            s = fmaf(wv.z, xs[k * 4 + 2], s);
            s = fmaf(wv.w, xs[k * 4 + 3], s);
        }
        partS[ic * 64 + o3] = s;
        __syncthreads();
        if (ic == 0) {
            float t = s;
#pragma unroll
            for (int p = 1; p < 8; p++) t += partS[p * 64 + o3];
            float g = 0.f;
#pragma unroll
            for (int r = 0; r < 4; r++)
                g += ld_c(ws + OFF_AGG3 + r * 2240 + n * 64 + o3);
            const float c = fmaxf(cS[0], 1.f);
            st_c(ws + OFF_X3 + n * 64 + o3, fmaxf(g / c + t + b3[o3], 0.f));
        }
        // 35-way flag: x3 stores drained by __syncthreads (vmcnt), then arrive
        __syncthreads();
        if (tid == 0) {
            unsigned* flag = bar + 256;
            __hip_atomic_fetch_add(flag, 1u, __ATOMIC_RELAXED,
                                   __HIP_MEMORY_SCOPE_AGENT);
            while (__hip_atomic_load(flag, __ATOMIC_RELAXED,
                                     __HIP_MEMORY_SCOPE_AGENT) < NN)
                __builtin_amdgcn_s_sleep(4);
            asm volatile("" ::: "memory");
        }
        __syncthreads();
        // CBT
        float* sx = smem;  // 2240
        for (int idx = tid; idx < NN * 32; idx += 512)
            *(float2*)&sx[idx * 2] = ld_c2(ws + OFF_X3 + idx * 2);
        __syncthreads();
        const int f = tid & 63, jg = tid >> 6;
        const float xi = sx[bid * 64 + f];
        for (int j = jg; j < NN; j += 8) {
            float d = fabsf(xi - sx[j * 64 + f]);
#pragma unroll
            for (int off = 32; off > 0; off >>= 1) d += __shfl_xor(d, off);
            if (f == 0) out[bid * NN + j] = d;
        }
    }
}

extern "C" void kernel_launch(void* const* d_in, const int* in_sizes, int n_in,
                              void* d_out, int out_size, void* d_ws, size_t ws_size,
                              hipStream_t stream) {
    (void)in_sizes; (void)n_in; (void)out_size; (void)ws_size;
    const float* x    = (const float*)d_in[0];
    const float* ea   = (const float*)d_in[1];
    const int*   ei   = (const int*)d_in[2];
    const float* nn1w = (const float*)d_in[3];
    const float* nn1b = (const float*)d_in[4];
    const float* lin1 = (const float*)d_in[5];
    const float* b1   = (const float*)d_in[6];
    const float* nn2w = (const float*)d_in[7];
    const float* nn2b = (const float*)d_in[8];
    const float* lin2 = (const float*)d_in[9];
    const float* b2   = (const float*)d_in[10];
    const float* nn3w = (const float*)d_in[11];
    const float* nn3b = (const float*)d_in[12];
    const float* lin3 = (const float*)d_in[13];
    const float* b3   = (const float*)d_in[14];

    float* ws = (float*)d_ws;
    init_k<<<1, 64, 0, stream>>>((unsigned*)d_ws);
    mega_k<<<NBLK, 512, 0, stream>>>(ws, x, ea, ei, nn1w, nn1b, lin1, b1,
                                     nn2w, nn2b, lin2, b2, nn3w, nn3b,
                                     lin3, b3, (float*)d_out);
}

// Round 6
// 147.226 us; speedup vs baseline: 1.0764x; 1.0764x over previous
//
#include <hip/hip_runtime.h>

// MGN_NET: 3x NNConv(mean) + ReLU, then pairwise-L1 CBT [35x35]. All fp32.
// 2 dispatches: init (zero barrier counters) + mega-kernel (224 blocks x 512)
// with 3 software grid barriers + one 35-way flag.
// R5 -> R6: destination-centric layers 2/3. A block owns (node, o-slice),
// stages the node's in-edge x1 rows in LDS, holds the 4x7 edge-MLP weight
// words in registers (each (i,o) weight read ONCE per item), reduces over
// edges in registers, and writes x2[n,o] end-to-end. Eliminates: the PC
// gather phase + 1 grid barrier, all 609K agg2 atomics + replicas + zeroing,
// and the 119x weight re-stream of edge-centric PB.
// Grid 224 <= 256 CUs: 1 block/CU, no double-loaded CU stragglers,
// co-residency (and thus barrier liveness) is unconditional.
// Phases:
//   P1 (140 blk = 35n x 4og): edge lists -> ws; x1 slices; 84 blk zero agg3
//   P2 (560 items = 35n x 16os, 2-3/blk): x2[n, 16-o] complete, no atomics
//   P3 (280 items = 35n x 8iq, 1-2/blk): layer-3 i-partials -> agg3 (18K at.)
//   P4 (35 blk): x3 = relu(agg3/c + lin3.x2 + b3); 35-flag; CBT -> out
// Coherence: ws intermediates via agent-scope relaxed atomics (sc1 -> LLC);
// read-only inputs via plain cached loads. Barriers fence-free
// (__syncthreads drains vmcnt; sc1 ops complete at LLC).

#define NN 35
#define NE 1190
#define NBLK 224
#define MAXE 96

// float offsets into ws (u32 bar region [0,320): 16 lines + flag@256)
#define OFF_CNT  320     // 35
#define OFF_EL   384     // ints, 35*96 = 3360 -> ends 3744
#define OFF_X1   3840    // 8960 -> 12800
#define OFF_X2   12800   // 8960 -> 21760
#define OFF_X3   21760   // 2240 -> 24000
#define OFF_AGG3 24064   // 2240 -> 26304

__global__ __launch_bounds__(64) void init_k(unsigned* bar) {
    for (int i = threadIdx.x; i < 320; i += 64) bar[i] = 0u;
}

// Agent-scope (LLC-coherent, sc1) relaxed accessors.
__device__ __forceinline__ float ld_c(const float* p) {
    return __hip_atomic_load(p, __ATOMIC_RELAXED, __HIP_MEMORY_SCOPE_AGENT);
}
__device__ __forceinline__ void st_c(float* p, float v) {
    __hip_atomic_store(p, v, __ATOMIC_RELAXED, __HIP_MEMORY_SCOPE_AGENT);
}
__device__ __forceinline__ int ld_ci(const int* p) {
    return __hip_atomic_load(p, __ATOMIC_RELAXED, __HIP_MEMORY_SCOPE_AGENT);
}
__device__ __forceinline__ void st_ci(int* p, int v) {
    __hip_atomic_store(p, v, __ATOMIC_RELAXED, __HIP_MEMORY_SCOPE_AGENT);
}
__device__ __forceinline__ float2 ld_c2(const float* p) {
    union { double d; float2 f; } u;
    u.d = __hip_atomic_load((const double*)p, __ATOMIC_RELAXED,
                            __HIP_MEMORY_SCOPE_AGENT);
    return u.f;
}
__device__ __forceinline__ void st_c2(float* p, float2 v) {
    union { double d; float2 f; } u;
    u.f = v;
    __hip_atomic_store((double*)p, u.d, __ATOMIC_RELAXED,
                       __HIP_MEMORY_SCOPE_AGENT);
}

// Grid barrier: 16 counters on 16 distinct 64B lines; sum-poll (correct by
// induction on rounds since counters are monotonic).
__device__ __forceinline__ void gbar(unsigned* bar, unsigned target) {
    __syncthreads();
    if (threadIdx.x == 0) {
        __hip_atomic_fetch_add(bar + (blockIdx.x & 15) * 16, 1u,
                               __ATOMIC_RELAXED, __HIP_MEMORY_SCOPE_AGENT);
        for (;;) {
            unsigned s = 0;
#pragma unroll
            for (int i = 0; i < 16; i++)
                s += __hip_atomic_load(bar + i * 16, __ATOMIC_RELAXED,
                                       __HIP_MEMORY_SCOPE_AGENT);
            if (s >= target) break;
            __builtin_amdgcn_s_sleep(8);
        }
        asm volatile("" ::: "memory");
    }
    __syncthreads();
}

__global__ __launch_bounds__(512, 2) void mega_k(
    float* __restrict__ ws, const float* __restrict__ x,
    const float* __restrict__ ea, const int* __restrict__ ei,
    const float* __restrict__ w1, const float* __restrict__ b1w,
    const float* __restrict__ lin1, const float* __restrict__ b1,
    const float* __restrict__ w2, const float* __restrict__ b2w,
    const float* __restrict__ lin2, const float* __restrict__ b2,
    const float* __restrict__ w3, const float* __restrict__ b3w,
    const float* __restrict__ lin3, const float* __restrict__ b3,
    float* __restrict__ out) {
    __shared__ float smem[14400];  // 57.6 KiB, re-purposed per phase
    unsigned* bar = (unsigned*)ws;
    const int tid = threadIdx.x;
    const int bid = blockIdx.x;

    // ---------------- P1: edge lists + x1 slices + agg3 zero ---------------
    if (bid < 140) {
        const int n = bid >> 2, och = bid & 3;
        int* elistS = (int*)smem;            // 96
        int* ecntS = (int*)smem + 96;        // 1
        float* partS = smem + 128;           // 8*64
        if (tid == 0) *ecntS = 0;
        __syncthreads();
        for (int e = tid; e < NE; e += 512) {
            if (ei[NE + e] == n) {
                const int p = atomicAdd(ecntS, 1);
                if (p < MAXE) elistS[p] = e;
            }
        }
        __syncthreads();
        const int deg = *ecntS;
        const int dl = deg < MAXE ? deg : MAXE;
        const int ol = tid & 63, ech = tid >> 6;
        const int o = och * 64 + ol;
        const float2* wr = (const float2*)(w1 + o * 6);
        const float2 wv0 = wr[0], wv1 = wr[1], wv2 = wr[2];
        const float bb = b1w[o];
        float a = 0.f;
        for (int k = ech; k < dl; k += 8) {
            const int e = elistS[k];
            const float2* eap = (const float2*)(ea + e * 6);
            const float2 a0 = eap[0], a1 = eap[1], a2 = eap[2];
            float d = bb;
            d = fmaf(a0.x, wv0.x, d); d = fmaf(a0.y, wv0.y, d);
            d = fmaf(a1.x, wv1.x, d); d = fmaf(a1.y, wv1.y, d);
            d = fmaf(a2.x, wv2.x, d); d = fmaf(a2.y, wv2.y, d);
            a = fmaf(x[ei[e]], fmaxf(d, 0.f), a);
        }
        partS[ech * 64 + ol] = a;
        __syncthreads();
        if (ech == 0) {
            float s = a;
#pragma unroll
            for (int p = 1; p < 8; p++) s += partS[p * 64 + ol];
            const float c = fmaxf((float)deg, 1.f);
            st_c(ws + OFF_X1 + n * 256 + o,
                 fmaxf(s / c + x[n] * lin1[o] + b1[o], 0.f));
        }
        if (och == 0) {
            if (tid < dl) st_ci((int*)(ws + OFF_EL) + n * MAXE + tid, elistS[tid]);
            if (tid == 0) st_c(ws + OFF_CNT + n, (float)deg);
        }
    } else {
        const int idx = (bid - 140) * 512 + tid;
        if (idx < NN * 64) st_c(ws + OFF_AGG3 + idx, 0.f);
    }
    gbar(bar, NBLK * 1u);

    // ------- P2: dst-centric layer 2 -> x2[n, 16-o slice], no atomics ------
    {
        float* xsS = smem;                    // 96*128 = 12288
        float* x1S = smem + 12288;            // 256
        float* easS = smem + 12544;           // 96*6 = 576
        int* srcS = (int*)(smem + 13120);     // 96
        int* elS  = (int*)(smem + 13216);     // 96
        float* cS = smem + 13312;             // 1
        float* partA = smem + 13376;          // 32*16 = 512
        float* partB = smem + 13888;          // 32*16 = 512
        const int ol = tid & 15, ic = tid >> 4;  // 16 o-lanes x 32 i-chunks
        for (int it = bid; it < NN * 16; it += NBLK) {
            const int n = it >> 4, og = it & 15;
            const int o = og * 16 + ol;
            __syncthreads();  // protect smem reuse from previous item
            if (tid == 0) cS[0] = ld_c(ws + OFF_CNT + n);
            if (tid < MAXE)
                elS[tid] = ld_ci((const int*)(ws + OFF_EL) + n * MAXE + tid);
            if (tid >= 128 && tid < 256) {
                const int ip = (tid - 128) * 2;
                *(float2*)&x1S[ip] = ld_c2(ws + OFF_X1 + n * 256 + ip);
            }
            __syncthreads();
            const int deg = (int)cS[0];
            const int dl = deg < MAXE ? deg : MAXE;
            if (tid < dl) {
                const int eid = elS[tid];
                srcS[tid] = ei[eid];
                const float2* eap = (const float2*)(ea + eid * 6);
                *(float2*)&easS[tid * 6] = eap[0];
                *(float2*)&easS[tid * 6 + 2] = eap[1];
                *(float2*)&easS[tid * 6 + 4] = eap[2];
            }
            float accm = 0.f;
            for (int p = 0; p < 2; ++p) {   // i-halves (LDS fits 96x128)
                __syncthreads();            // srcS ready (p=0) / xs reusable
                for (int idx = tid; idx < dl * 64; idx += 512) {
                    const int e = idx >> 6, ip = (idx & 63) * 2;
                    *(float2*)&xsS[e * 128 + ip] =
                        ld_c2(ws + OFF_X1 + srcS[e] * 256 + p * 128 + ip);
                }
                __syncthreads();
                const int i0 = p * 128 + ic * 4;
                const float* wp0 = w2 + (size_t)((i0 + 0) * 256 + o) * 6;
                const float* wp1 = w2 + (size_t)((i0 + 1) * 256 + o) * 6;
                const float* wp2 = w2 + (size_t)((i0 + 2) * 256 + o) * 6;
                const float* wp3 = w2 + (size_t)((i0 + 3) * 256 + o) * 6;
                const float2 wa0 = *(const float2*)wp0;
                const float2 wb0 = *(const float2*)(wp0 + 2);
                const float2 wc0 = *(const float2*)(wp0 + 4);
                const float2 wa1 = *(const float2*)wp1;
                const float2 wb1 = *(const float2*)(wp1 + 2);
                const float2 wc1 = *(const float2*)(wp1 + 4);
                const float2 wa2 = *(const float2*)wp2;
                const float2 wb2 = *(const float2*)(wp2 + 2);
                const float2 wc2 = *(const float2*)(wp2 + 4);
                const float2 wa3 = *(const float2*)wp3;
                const float2 wb3 = *(const float2*)(wp3 + 2);
                const float2 wc3 = *(const float2*)(wp3 + 4);
                const float bb0 = b2w[(i0 + 0) * 256 + o];
                const float bb1 = b2w[(i0 + 1) * 256 + o];
                const float bb2 = b2w[(i0 + 2) * 256 + o];
                const float bb3 = b2w[(i0 + 3) * 256 + o];
                for (int e = 0; e < dl; ++e) {
                    const float2 e01 = *(const float2*)&easS[e * 6];
                    const float2 e23 = *(const float2*)&easS[e * 6 + 2];
                    const float2 e45 = *(const float2*)&easS[e * 6 + 4];
                    const float4 xv = *(const float4*)&xsS[e * 128 + ic * 4];
                    float d0 = bb0, d1 = bb1, d2 = bb2, d3 = bb3;
                    d0 = fmaf(e01.x, wa0.x, d0); d1 = fmaf(e01.x, wa1.x, d1);
                    d2 = fmaf(e01.x, wa2.x, d2); d3 = fmaf(e01.x, wa3.x, d3);
                    d0 = fmaf(e01.y, wa0.y, d0); d1 = fmaf(e01.y, wa1.y, d1);
                    d2 = fmaf(e01.y, wa2.y, d2); d3 = fmaf(e01.y, wa3.y, d3);
                    d0 = fmaf(e23.x, wb0.x, d0); d1 = fmaf(e23.x, wb1.x, d1);
                    d2 = fmaf(e23.x, wb2.x, d2); d3 = fmaf(e23.x, wb3.x, d3);
                    d0 = fmaf(e23.y, wb0.y, d0); d1 = fmaf(e23.y, wb1.y, d1);
                    d2 = fmaf(e23.y, wb2.y, d2); d3 = fmaf(e23.y, wb3.y, d3);
                    d0 = fmaf(e45.x, wc0.x, d0); d1 = fmaf(e45.x, wc1.x, d1);
                    d2 = fmaf(e45.x, wc2.x, d2); d3 = fmaf(e45.x, wc3.x, d3);
                    d0 = fmaf(e45.y, wc0.y, d0); d1 = fmaf(e45.y, wc1.y, d1);
                    d2 = fmaf(e45.y, wc2.y, d2); d3 = fmaf(e45.y, wc3.y, d3);
                    d0 = fmaxf(d0, 0.f); d1 = fmaxf(d1, 0.f);
                    d2 = fmaxf(d2, 0.f); d3 = fmaxf(d3, 0.f);
                    accm = fmaf(xv.x, d0, accm);
                    accm = fmaf(xv.y, d1, accm);
                    accm = fmaf(xv.z, d2, accm);
                    accm = fmaf(xv.w, d3, accm);
                }
            }
            // root (lin2) partial over this thread's 8 i's
            float accl = 0.f;
            {
                const float4 l0 = *(const float4*)(lin2 + (size_t)o * 256 + ic * 4);
                const float4 xa = *(const float4*)&x1S[ic * 4];
                accl = fmaf(l0.x, xa.x, accl); accl = fmaf(l0.y, xa.y, accl);
                accl = fmaf(l0.z, xa.z, accl); accl = fmaf(l0.w, xa.w, accl);
                const float4 l1 =
                    *(const float4*)(lin2 + (size_t)o * 256 + 128 + ic * 4);
                const float4 xb = *(const float4*)&x1S[128 + ic * 4];
                accl = fmaf(l1.x, xb.x, accl); accl = fmaf(l1.y, xb.y, accl);
                accl = fmaf(l1.z, xb.z, accl); accl = fmaf(l1.w, xb.w, accl);
            }
            partA[ic * 16 + ol] = accm;
            partB[ic * 16 + ol] = accl;
            __syncthreads();
            if (tid < 16) {
                float m = 0.f, l = 0.f;
                for (int k = 0; k < 32; ++k) {
                    m += partA[k * 16 + tid];
                    l += partB[k * 16 + tid];
                }
                const float c = fmaxf(cS[0], 1.f);
                st_c(ws + OFF_X2 + n * 256 + og * 16 + tid,
                     fmaxf(m / c + l + b2[og * 16 + tid], 0.f));
            }
        }
    }
    gbar(bar, NBLK * 2u);

    // ------- P3: dst-centric layer-3 i-partials -> agg3 (18K atomics) ------
    {
        float* xsS = smem;                    // 96*32 = 3072
        float* easS = smem + 3072;            // 576
        int* srcS = (int*)(smem + 3648);      // 96
        int* elS  = (int*)(smem + 3744);      // 96
        float* cS = smem + 3840;              // 1
        float* partS = smem + 3904;           // 8*64 = 512
        const int ol = tid & 63, ic = tid >> 6;  // 64 o-lanes x 8 i-chunks
        for (int it = bid; it < NN * 8; it += NBLK) {
            const int n = it >> 3, iq = it & 7;
            const int i0 = iq * 32;
            __syncthreads();
            if (tid == 0) cS[0] = ld_c(ws + OFF_CNT + n);
            if (tid < MAXE)
                elS[tid] = ld_ci((const int*)(ws + OFF_EL) + n * MAXE + tid);
            __syncthreads();
            const int deg = (int)cS[0];
            const int dl = deg < MAXE ? deg : MAXE;
            if (tid < dl) {
                const int eid = elS[tid];
                srcS[tid] = ei[eid];
                const float2* eap = (const float2*)(ea + eid * 6);
                *(float2*)&easS[tid * 6] = eap[0];
                *(float2*)&easS[tid * 6 + 2] = eap[1];
                *(float2*)&easS[tid * 6 + 4] = eap[2];
            }
            __syncthreads();
            for (int idx = tid; idx < dl * 16; idx += 512) {
                const int e = idx >> 4, ip = (idx & 15) * 2;
                *(float2*)&xsS[e * 32 + ip] =
                    ld_c2(ws + OFF_X2 + srcS[e] * 256 + i0 + ip);
            }
            __syncthreads();
            const int ib = i0 + ic * 4;
            const float* wp0 = w3 + (size_t)((ib + 0) * 64 + ol) * 6;
            const float* wp1 = w3 + (size_t)((ib + 1) * 64 + ol) * 6;
            const float* wp2 = w3 + (size_t)((ib + 2) * 64 + ol) * 6;
            const float* wp3 = w3 + (size_t)((ib + 3) * 64 + ol) * 6;
            const float2 wa0 = *(const float2*)wp0;
            const float2 wb0 = *(const float2*)(wp0 + 2);
            const float2 wc0 = *(const float2*)(wp0 + 4);
            const float2 wa1 = *(const float2*)wp1;
            const float2 wb1 = *(const float2*)(wp1 + 2);
            const float2 wc1 = *(const float2*)(wp1 + 4);
            const float2 wa2 = *(const float2*)wp2;
            const float2 wb2 = *(const float2*)(wp2 + 2);
            const float2 wc2 = *(const float2*)(wp2 + 4);
            const float2 wa3 = *(const float2*)wp3;
            const float2 wb3 = *(const float2*)(wp3 + 2);
            const float2 wc3 = *(const float2*)(wp3 + 4);
            const float bb0 = b3w[(ib + 0) * 64 + ol];
            const float bb1 = b3w[(ib + 1) * 64 + ol];
            const float bb2 = b3w[(ib + 2) * 64 + ol];
            const float bb3 = b3w[(ib + 3) * 64 + ol];
            float accm = 0.f;
            for (int e = 0; e < dl; ++e) {
                const float2 e01 = *(const float2*)&easS[e * 6];
                const float2 e23 = *(const float2*)&easS[e * 6 + 2];
                const float2 e45 = *(const float2*)&easS[e * 6 + 4];
                const float4 xv = *(const float4*)&xsS[e * 32 + ic * 4];
                float d0 = bb0, d1 = bb1, d2 = bb2, d3 = bb3;
                d0 = fmaf(e01.x, wa0.x, d0); d1 = fmaf(e01.x, wa1.x, d1);
                d2 = fmaf(e01.x, wa2.x, d2); d3 = fmaf(e01.x, wa3.x, d3);
                d0 = fmaf(e01.y, wa0.y, d0); d1 = fmaf(e01.y, wa1.y, d1);
                d2 = fmaf(e01.y, wa2.y, d2); d3 = fmaf(e01.y, wa3.y, d3);
                d0 = fmaf(e23.x, wb0.x, d0); d1 = fmaf(e23.x, wb1.x, d1);
                d2 = fmaf(e23.x, wb2.x, d2); d3 = fmaf(e23.x, wb3.x, d3);
                d0 = fmaf(e23.y, wb0.y, d0); d1 = fmaf(e23.y, wb1.y, d1);
                d2 = fmaf(e23.y, wb2.y, d2); d3 = fmaf(e23.y, wb3.y, d3);
                d0 = fmaf(e45.x, wc0.x, d0); d1 = fmaf(e45.x, wc1.x, d1);
                d2 = fmaf(e45.x, wc2.x, d2); d3 = fmaf(e45.x, wc3.x, d3);
                d0 = fmaf(e45.y, wc0.y, d0); d1 = fmaf(e45.y, wc1.y, d1);
                d2 = fmaf(e45.y, wc2.y, d2); d3 = fmaf(e45.y, wc3.y, d3);
                d0 = fmaxf(d0, 0.f); d1 = fmaxf(d1, 0.f);
                d2 = fmaxf(d2, 0.f); d3 = fmaxf(d3, 0.f);
                accm = fmaf(xv.x, d0, accm);
                accm = fmaf(xv.y, d1, accm);
                accm = fmaf(xv.z, d2, accm);
                accm = fmaf(xv.w, d3, accm);
            }
            partS[ic * 64 + ol] = accm;
            __syncthreads();
            if (ic == 0) {
                float s = accm;
#pragma unroll
                for (int p = 1; p < 8; ++p) s += partS[p * 64 + ol];
                atomicAdd(ws + OFF_AGG3 + n * 64 + ol, s);
            }
        }
    }
    gbar(bar, NBLK * 3u);

    // ---------------- P4: x3 (own node) + 35-flag + CBT --------------------
    if (bid >= NN) return;
    {
        const int n = bid;
        float* x2S = smem;               // 256
        float* partS = smem + 256;       // 8*64
        float* cS = smem + 768;          // 1
        if (tid == 0) cS[0] = ld_c(ws + OFF_CNT + n);
        if (tid >= 128 && tid < 256) {
            const int ip = (tid - 128) * 2;
            *(float2*)&x2S[ip] = ld_c2(ws + OFF_X2 + n * 256 + ip);
        }
        __syncthreads();
        const int o3 = tid & 63, ic = tid >> 6;
        const float4* l4 = (const float4*)(lin3 + (size_t)o3 * 256 + ic * 32);
        const float* xs = x2S + ic * 32;
        float slin = 0.f;
#pragma unroll
        for (int k = 0; k < 8; k++) {
            const float4 wv = l4[k];
            slin = fmaf(wv.x, xs[k * 4], slin);
            slin = fmaf(wv.y, xs[k * 4 + 1], slin);
            slin = fmaf(wv.z, xs[k * 4 + 2], slin);
            slin = fmaf(wv.w, xs[k * 4 + 3], slin);
        }
        partS[ic * 64 + o3] = slin;
        __syncthreads();
        if (ic == 0) {
            float s = slin;
#pragma unroll
            for (int p = 1; p < 8; p++) s += partS[p * 64 + o3];
            const float g = ld_c(ws + OFF_AGG3 + n * 64 + o3);
            const float c = fmaxf(cS[0], 1.f);
            st_c(ws + OFF_X3 + n * 64 + o3, fmaxf(g / c + s + b3[o3], 0.f));
        }
        __syncthreads();  // drains the x3 sc1 stores (vmcnt) before arrival
        if (tid == 0) {
            unsigned* flag = bar + 256;
            __hip_atomic_fetch_add(flag, 1u, __ATOMIC_RELAXED,
                                   __HIP_MEMORY_SCOPE_AGENT);
            while (__hip_atomic_load(flag, __ATOMIC_RELAXED,
                                     __HIP_MEMORY_SCOPE_AGENT) < NN)
                __builtin_amdgcn_s_sleep(4);
            asm volatile("" ::: "memory");
        }
        __syncthreads();
        float* sx = smem;  // 2240
        for (int idx = tid; idx < NN * 32; idx += 512)
            *(float2*)&sx[idx * 2] = ld_c2(ws + OFF_X3 + idx * 2);
        __syncthreads();
        const int f = tid & 63, jg = tid >> 6;
        const float xi = sx[n * 64 + f];
        for (int j = jg; j < NN; j += 8) {
            float d = fabsf(xi - sx[j * 64 + f]);
#pragma unroll
            for (int off = 32; off > 0; off >>= 1) d += __shfl_xor(d, off);
            if (f == 0) out[n * NN + j] = d;
        }
    }
}

extern "C" void kernel_launch(void* const* d_in, const int* in_sizes, int n_in,
                              void* d_out, int out_size, void* d_ws, size_t ws_size,
                              hipStream_t stream) {
    (void)in_sizes; (void)n_in; (void)out_size; (void)ws_size;
    const float* x    = (const float*)d_in[0];
    const float* ea   = (const float*)d_in[1];
    const int*   ei   = (const int*)d_in[2];
    const float* nn1w = (const float*)d_in[3];
    const float* nn1b = (const float*)d_in[4];
    const float* lin1 = (const float*)d_in[5];
    const float* b1   = (const float*)d_in[6];
    const float* nn2w = (const float*)d_in[7];
    const float* nn2b = (const float*)d_in[8];
    const float* lin2 = (const float*)d_in[9];
    const float* b2   = (const float*)d_in[10];
    const float* nn3w = (const float*)d_in[11];
    const float* nn3b = (const float*)d_in[12];
    const float* lin3 = (const float*)d_in[13];
    const float* b3   = (const float*)d_in[14];

    float* ws = (float*)d_ws;
    init_k<<<1, 64, 0, stream>>>((unsigned*)d_ws);
    mega_k<<<NBLK, 512, 0, stream>>>(ws, x, ea, ei, nn1w, nn1b, lin1, b1,
                                     nn2w, nn2b, lin2, b2, nn3w, nn3b,
                                     lin3, b3, (float*)d_out);
}

// Round 7
// 125.979 us; speedup vs baseline: 1.2580x; 1.1687x over previous
//
#include <hip/hip_runtime.h>

// MGN_NET: 3x NNConv(mean) + ReLU, then pairwise-L1 CBT [35x35]. All fp32.
// R6 -> R7: same dst-centric algorithm, but back to SEPARATE DISPATCHES.
// Measured overhead model: dur_us - kernel_time ~= 78 us constant (2 poison
// fills), launch gaps are ~1-2 us -> software grid barriers + sc1-coherent
// traffic were pure overhead. Kernel boundaries give free device-wide
// ordering/coherence, so all loads/stores are plain cached ops, and each
// phase can use its ideal grid:
//   x1_k  (145 blk): edge lists + deg -> ws; x1 slices; blocks 140+ zero agg3
//   x2_k  (560 blk = 35n x 16og, 1 item/blk): x2[n, 16-o] end-to-end,
//          weights read once per (i,o), no atomics, perfect balance
//   p3_k  (280 blk = 35n x 8iq): layer-3 i-quarter partials -> agg3 atomics
//   x3_k  (35 blk): x3 = relu(agg3/c + lin3.x2 + b3)
//   cbt_k (35 blk): pairwise-L1 CBT -> out

#define NN 35
#define NE 1190
#define MAXE 80

// float offsets into ws
#define OFF_CNT  0       // 35
#define OFF_EL   64      // ints, 35*80 = 2800 -> ends 2864
#define OFF_X1   2944    // 8960 -> 11904
#define OFF_X2   11904   // 8960 -> 20864
#define OFF_X3   20864   // 2240 -> 23104
#define OFF_AGG3 23168   // 2240 -> 25408

// ---------------- K1: edge lists + x1 slices + agg3 zero -------------------
__global__ __launch_bounds__(512) void x1_k(
    float* __restrict__ ws, const float* __restrict__ x,
    const float* __restrict__ ea, const int* __restrict__ ei,
    const float* __restrict__ w1, const float* __restrict__ b1w,
    const float* __restrict__ lin1, const float* __restrict__ b1) {
    __shared__ int elistS[MAXE];
    __shared__ int ecntS;
    __shared__ float partS[8 * 64];
    const int tid = threadIdx.x, bid = blockIdx.x;
    if (bid >= 140) {
        const int idx = (bid - 140) * 512 + tid;
        if (idx < NN * 64) ws[OFF_AGG3 + idx] = 0.f;
        return;
    }
    const int n = bid >> 2, och = bid & 3;
    if (tid == 0) ecntS = 0;
    __syncthreads();
    for (int e = tid; e < NE; e += 512) {
        if (ei[NE + e] == n) {
            const int p = atomicAdd(&ecntS, 1);
            if (p < MAXE) elistS[p] = e;
        }
    }
    __syncthreads();
    const int deg = ecntS;
    const int dl = deg < MAXE ? deg : MAXE;
    const int ol = tid & 63, ech = tid >> 6;
    const int o = och * 64 + ol;
    const float2* wr = (const float2*)(w1 + o * 6);
    const float2 wv0 = wr[0], wv1 = wr[1], wv2 = wr[2];
    const float bb = b1w[o];
    float a = 0.f;
    for (int k = ech; k < dl; k += 8) {
        const int e = elistS[k];
        const float2* eap = (const float2*)(ea + e * 6);
        const float2 a0 = eap[0], a1 = eap[1], a2 = eap[2];
        float d = bb;
        d = fmaf(a0.x, wv0.x, d); d = fmaf(a0.y, wv0.y, d);
        d = fmaf(a1.x, wv1.x, d); d = fmaf(a1.y, wv1.y, d);
        d = fmaf(a2.x, wv2.x, d); d = fmaf(a2.y, wv2.y, d);
        a = fmaf(x[ei[e]], fmaxf(d, 0.f), a);
    }
    partS[ech * 64 + ol] = a;
    __syncthreads();
    if (ech == 0) {
        float s = a;
#pragma unroll
        for (int p = 1; p < 8; p++) s += partS[p * 64 + ol];
        const float c = fmaxf((float)deg, 1.f);
        ws[OFF_X1 + n * 256 + o] = fmaxf(s / c + x[n] * lin1[o] + b1[o], 0.f);
    }
    if (och == 0) {
        if (tid < dl) ((int*)(ws + OFF_EL))[n * MAXE + tid] = elistS[tid];
        if (tid == 0) ws[OFF_CNT + n] = (float)deg;
    }
}

// ---------------- K2: dst-centric layer 2 -> x2[n, 16-o slice] -------------
__global__ __launch_bounds__(512) void x2_k(
    float* __restrict__ ws, const float* __restrict__ ea,
    const int* __restrict__ ei, const float* __restrict__ w2,
    const float* __restrict__ b2w, const float* __restrict__ lin2,
    const float* __restrict__ b2) {
    __shared__ float smem[11264];          // 45 KiB -> 3 blocks/CU
    float* xsS = smem;                     // 80*128 = 10240
    float* x1S = smem + 10240;             // 256
    float* easS = smem + 10496;            // 480
    int* srcS = (int*)(smem + 10976);      // 80
    int* elS = (int*)(smem + 11056);       // 80
    float* partA = smem;                   // alias xsS (used after compute)
    float* partB = smem + 512;
    __shared__ float cS;
    const int tid = threadIdx.x;
    const int n = blockIdx.x >> 4, og = blockIdx.x & 15;
    const int ol = tid & 15, ic = tid >> 4;   // 16 o-lanes x 32 i-chunks(4)
    const int o = og * 16 + ol;
    if (tid == 0) cS = ws[OFF_CNT + n];
    if (tid < MAXE) elS[tid] = ((const int*)(ws + OFF_EL))[n * MAXE + tid];
    if (tid >= 448) {
        const int q = tid - 448;
        *(float4*)&x1S[q * 4] = *(const float4*)(ws + OFF_X1 + n * 256 + q * 4);
    }
    __syncthreads();
    const int deg = (int)cS;
    const int dl = deg < MAXE ? deg : MAXE;
    if (tid < dl) {
        const int eid = elS[tid];
        srcS[tid] = ei[eid];
        const float2* eap = (const float2*)(ea + eid * 6);
        *(float2*)&easS[tid * 6] = eap[0];
        *(float2*)&easS[tid * 6 + 2] = eap[1];
        *(float2*)&easS[tid * 6 + 4] = eap[2];
    }
    float accm = 0.f;
    for (int p = 0; p < 2; ++p) {          // i-halves of 128
        __syncthreads();                   // srcS/easS ready; xs reusable
        for (int idx = tid; idx < dl * 32; idx += 512) {
            const int e = idx >> 5, ip = (idx & 31) * 4;
            *(float4*)&xsS[e * 128 + ip] =
                *(const float4*)(ws + OFF_X1 + srcS[e] * 256 + p * 128 + ip);
        }
        __syncthreads();
        const int i0 = p * 128 + ic * 4;
        const float* wp0 = w2 + (size_t)((i0 + 0) * 256 + o) * 6;
        const float* wp1 = w2 + (size_t)((i0 + 1) * 256 + o) * 6;
        const float* wp2 = w2 + (size_t)((i0 + 2) * 256 + o) * 6;
        const float* wp3 = w2 + (size_t)((i0 + 3) * 256 + o) * 6;
        const float2 wa0 = *(const float2*)wp0;
        const float2 wb0 = *(const float2*)(wp0 + 2);
        const float2 wc0 = *(const float2*)(wp0 + 4);
        const float2 wa1 = *(const float2*)wp1;
        const float2 wb1 = *(const float2*)(wp1 + 2);
        const float2 wc1 = *(const float2*)(wp1 + 4);
        const float2 wa2 = *(const float2*)wp2;
        const float2 wb2 = *(const float2*)(wp2 + 2);
        const float2 wc2 = *(const float2*)(wp2 + 4);
        const float2 wa3 = *(const float2*)wp3;
        const float2 wb3 = *(const float2*)(wp3 + 2);
        const float2 wc3 = *(const float2*)(wp3 + 4);
        const float bb0 = b2w[(i0 + 0) * 256 + o];
        const float bb1 = b2w[(i0 + 1) * 256 + o];
        const float bb2 = b2w[(i0 + 2) * 256 + o];
        const float bb3 = b2w[(i0 + 3) * 256 + o];
        for (int e = 0; e < dl; ++e) {
            const float2 e01 = *(const float2*)&easS[e * 6];
            const float2 e23 = *(const float2*)&easS[e * 6 + 2];
            const float2 e45 = *(const float2*)&easS[e * 6 + 4];
            const float4 xv = *(const float4*)&xsS[e * 128 + ic * 4];
            float d0 = bb0, d1 = bb1, d2 = bb2, d3 = bb3;
            d0 = fmaf(e01.x, wa0.x, d0); d1 = fmaf(e01.x, wa1.x, d1);
            d2 = fmaf(e01.x, wa2.x, d2); d3 = fmaf(e01.x, wa3.x, d3);
            d0 = fmaf(e01.y, wa0.y, d0); d1 = fmaf(e01.y, wa1.y, d1);
            d2 = fmaf(e01.y, wa2.y, d2); d3 = fmaf(e01.y, wa3.y, d3);
            d0 = fmaf(e23.x, wb0.x, d0); d1 = fmaf(e23.x, wb1.x, d1);
            d2 = fmaf(e23.x, wb2.x, d2); d3 = fmaf(e23.x, wb3.x, d3);
            d0 = fmaf(e23.y, wb0.y, d0); d1 = fmaf(e23.y, wb1.y, d1);
            d2 = fmaf(e23.y, wb2.y, d2); d3 = fmaf(e23.y, wb3.y, d3);
            d0 = fmaf(e45.x, wc0.x, d0); d1 = fmaf(e45.x, wc1.x, d1);
            d2 = fmaf(e45.x, wc2.x, d2); d3 = fmaf(e45.x, wc3.x, d3);
            d0 = fmaf(e45.y, wc0.y, d0); d1 = fmaf(e45.y, wc1.y, d1);
            d2 = fmaf(e45.y, wc2.y, d2); d3 = fmaf(e45.y, wc3.y, d3);
            d0 = fmaxf(d0, 0.f); d1 = fmaxf(d1, 0.f);
            d2 = fmaxf(d2, 0.f); d3 = fmaxf(d3, 0.f);
            accm = fmaf(xv.x, d0, accm);
            accm = fmaf(xv.y, d1, accm);
            accm = fmaf(xv.z, d2, accm);
            accm = fmaf(xv.w, d3, accm);
        }
    }
    // root (lin2) partial over this thread's 8 i's
    float accl = 0.f;
    {
        const float4 l0 = *(const float4*)(lin2 + (size_t)o * 256 + ic * 4);
        const float4 xa = *(const float4*)&x1S[ic * 4];
        accl = fmaf(l0.x, xa.x, accl); accl = fmaf(l0.y, xa.y, accl);
        accl = fmaf(l0.z, xa.z, accl); accl = fmaf(l0.w, xa.w, accl);
        const float4 l1 = *(const float4*)(lin2 + (size_t)o * 256 + 128 + ic * 4);
        const float4 xb = *(const float4*)&x1S[128 + ic * 4];
        accl = fmaf(l1.x, xb.x, accl); accl = fmaf(l1.y, xb.y, accl);
        accl = fmaf(l1.z, xb.z, accl); accl = fmaf(l1.w, xb.w, accl);
    }
    __syncthreads();                 // all xs reads done; partA aliases xsS
    partA[ic * 16 + ol] = accm;
    partB[ic * 16 + ol] = accl;
    __syncthreads();
    if (tid < 16) {
        float m = 0.f, l = 0.f;
        for (int k = 0; k < 32; ++k) {
            m += partA[k * 16 + tid];
            l += partB[k * 16 + tid];
        }
        const float c = fmaxf(cS, 1.f);
        ws[OFF_X2 + n * 256 + og * 16 + tid] =
            fmaxf(m / c + l + b2[og * 16 + tid], 0.f);
    }
}

// ---------------- K3: layer-3 i-quarter partials -> agg3 -------------------
__global__ __launch_bounds__(512) void p3_k(
    float* __restrict__ ws, const float* __restrict__ ea,
    const int* __restrict__ ei, const float* __restrict__ w3,
    const float* __restrict__ b3w) {
    __shared__ float xsS[MAXE * 32];       // 2560
    __shared__ float easS[MAXE * 6];       // 480
    __shared__ int srcS[MAXE];
    __shared__ int elS[MAXE];
    __shared__ float partS[8 * 64];
    __shared__ float cS;
    const int tid = threadIdx.x;
    const int n = blockIdx.x >> 3, iq = blockIdx.x & 7;
    const int i0 = iq * 32;
    const int ol = tid & 63, ic = tid >> 6;   // 64 o-lanes x 8 i-chunks(4)
    if (tid == 0) cS = ws[OFF_CNT + n];
    if (tid < MAXE) elS[tid] = ((const int*)(ws + OFF_EL))[n * MAXE + tid];
    __syncthreads();
    const int deg = (int)cS;
    const int dl = deg < MAXE ? deg : MAXE;
    if (tid < dl) {
        const int eid = elS[tid];
        srcS[tid] = ei[eid];
        const float2* eap = (const float2*)(ea + eid * 6);
        *(float2*)&easS[tid * 6] = eap[0];
        *(float2*)&easS[tid * 6 + 2] = eap[1];
        *(float2*)&easS[tid * 6 + 4] = eap[2];
    }
    __syncthreads();
    for (int idx = tid; idx < dl * 8; idx += 512) {
        const int e = idx >> 3, ip = (idx & 7) * 4;
        *(float4*)&xsS[e * 32 + ip] =
            *(const float4*)(ws + OFF_X2 + srcS[e] * 256 + i0 + ip);
    }
    __syncthreads();
    const int ib = i0 + ic * 4;
    const float* wp0 = w3 + (size_t)((ib + 0) * 64 + ol) * 6;
    const float* wp1 = w3 + (size_t)((ib + 1) * 64 + ol) * 6;
    const float* wp2 = w3 + (size_t)((ib + 2) * 64 + ol) * 6;
    const float* wp3 = w3 + (size_t)((ib + 3) * 64 + ol) * 6;
    const float2 wa0 = *(const float2*)wp0;
    const float2 wb0 = *(const float2*)(wp0 + 2);
    const float2 wc0 = *(const float2*)(wp0 + 4);
    const float2 wa1 = *(const float2*)wp1;
    const float2 wb1 = *(const float2*)(wp1 + 2);
    const float2 wc1 = *(const float2*)(wp1 + 4);
    const float2 wa2 = *(const float2*)wp2;
    const float2 wb2 = *(const float2*)(wp2 + 2);
    const float2 wc2 = *(const float2*)(wp2 + 4);
    const float2 wa3 = *(const float2*)wp3;
    const float2 wb3 = *(const float2*)(wp3 + 2);
    const float2 wc3 = *(const float2*)(wp3 + 4);
    const float bb0 = b3w[(ib + 0) * 64 + ol];
    const float bb1 = b3w[(ib + 1) * 64 + ol];
    const float bb2 = b3w[(ib + 2) * 64 + ol];
    const float bb3 = b3w[(ib + 3) * 64 + ol];
    float accm = 0.f;
    for (int e = 0; e < dl; ++e) {
        const float2 e01 = *(const float2*)&easS[e * 6];
        const float2 e23 = *(const float2*)&easS[e * 6 + 2];
        const float2 e45 = *(const float2*)&easS[e * 6 + 4];
        const float4 xv = *(const float4*)&xsS[e * 32 + ic * 4];
        float d0 = bb0, d1 = bb1, d2 = bb2, d3 = bb3;
        d0 = fmaf(e01.x, wa0.x, d0); d1 = fmaf(e01.x, wa1.x, d1);
        d2 = fmaf(e01.x, wa2.x, d2); d3 = fmaf(e01.x, wa3.x, d3);
        d0 = fmaf(e01.y, wa0.y, d0); d1 = fmaf(e01.y, wa1.y, d1);
        d2 = fmaf(e01.y, wa2.y, d2); d3 = fmaf(e01.y, wa3.y, d3);
        d0 = fmaf(e23.x, wb0.x, d0); d1 = fmaf(e23.x, wb1.x, d1);
        d2 = fmaf(e23.x, wb2.x, d2); d3 = fmaf(e23.x, wb3.x, d3);
        d0 = fmaf(e23.y, wb0.y, d0); d1 = fmaf(e23.y, wb1.y, d1);
        d2 = fmaf(e23.y, wb2.y, d2); d3 = fmaf(e23.y, wb3.y, d3);
        d0 = fmaf(e45.x, wc0.x, d0); d1 = fmaf(e45.x, wc1.x, d1);
        d2 = fmaf(e45.x, wc2.x, d2); d3 = fmaf(e45.x, wc3.x, d3);
        d0 = fmaf(e45.y, wc0.y, d0); d1 = fmaf(e45.y, wc1.y, d1);
        d2 = fmaf(e45.y, wc2.y, d2); d3 = fmaf(e45.y, wc3.y, d3);
        d0 = fmaxf(d0, 0.f); d1 = fmaxf(d1, 0.f);
        d2 = fmaxf(d2, 0.f); d3 = fmaxf(d3, 0.f);
        accm = fmaf(xv.x, d0, accm);
        accm = fmaf(xv.y, d1, accm);
        accm = fmaf(xv.z, d2, accm);
        accm = fmaf(xv.w, d3, accm);
    }
    partS[ic * 64 + ol] = accm;
    __syncthreads();
    if (ic == 0) {
        float s = accm;
#pragma unroll
        for (int p = 1; p < 8; ++p) s += partS[p * 64 + ol];
        atomicAdd(ws + OFF_AGG3 + n * 64 + ol, s);
    }
}

// ---------------- K4: x3 = relu(agg3/c + lin3.x2 + b3) ---------------------
__global__ __launch_bounds__(256) void x3_k(float* __restrict__ ws,
                                            const float* __restrict__ lin3,
                                            const float* __restrict__ b3) {
    __shared__ float x2S[256];
    __shared__ float partS[3 * 64];
    __shared__ float cS;
    const int n = blockIdx.x, tid = threadIdx.x;
    const int o3 = tid & 63, ic = tid >> 6;   // 4 chunks of 64 i
    if (tid == 0) cS = ws[OFF_CNT + n];
    if (tid < 64)
        *(float4*)&x2S[tid * 4] = *(const float4*)(ws + OFF_X2 + n * 256 + tid * 4);
    __syncthreads();
    const float4* l4 = (const float4*)(lin3 + (size_t)o3 * 256 + ic * 64);
    float s = 0.f;
#pragma unroll
    for (int k = 0; k < 16; k++) {
        const float4 wv = l4[k];
        const int i = ic * 64 + k * 4;
        s = fmaf(wv.x, x2S[i], s);
        s = fmaf(wv.y, x2S[i + 1], s);
        s = fmaf(wv.z, x2S[i + 2], s);
        s = fmaf(wv.w, x2S[i + 3], s);
    }
    if (ic > 0) partS[(ic - 1) * 64 + o3] = s;
    __syncthreads();
    if (ic == 0) {
        const float tot = s + partS[o3] + partS[64 + o3] + partS[128 + o3];
        const float c = fmaxf(cS, 1.f);
        ws[OFF_X3 + n * 64 + o3] =
            fmaxf(ws[OFF_AGG3 + n * 64 + o3] / c + tot + b3[o3], 0.f);
    }
}

// ---------------- K5: pairwise-L1 CBT --------------------------------------
__global__ __launch_bounds__(512) void cbt_k(const float* __restrict__ ws,
                                             float* __restrict__ out) {
    __shared__ float sx[NN * 64];
    const int tid = threadIdx.x;
    for (int idx = tid; idx < NN * 16; idx += 512)
        *(float4*)&sx[idx * 4] = *(const float4*)(ws + OFF_X3 + idx * 4);
    __syncthreads();
    const int f = tid & 63, jg = tid >> 6;
    const float xi = sx[blockIdx.x * 64 + f];
    for (int j = jg; j < NN; j += 8) {
        float d = fabsf(xi - sx[j * 64 + f]);
#pragma unroll
        for (int off = 32; off > 0; off >>= 1) d += __shfl_xor(d, off);
        if (f == 0) out[blockIdx.x * NN + j] = d;
    }
}

extern "C" void kernel_launch(void* const* d_in, const int* in_sizes, int n_in,
                              void* d_out, int out_size, void* d_ws, size_t ws_size,
                              hipStream_t stream) {
    (void)in_sizes; (void)n_in; (void)out_size; (void)ws_size;
    const float* x    = (const float*)d_in[0];
    const float* ea   = (const float*)d_in[1];
    const int*   ei   = (const int*)d_in[2];
    const float* nn1w = (const float*)d_in[3];
    const float* nn1b = (const float*)d_in[4];
    const float* lin1 = (const float*)d_in[5];
    const float* b1   = (const float*)d_in[6];
    const float* nn2w = (const float*)d_in[7];
    const float* nn2b = (const float*)d_in[8];
    const float* lin2 = (const float*)d_in[9];
    const float* b2   = (const float*)d_in[10];
    const float* nn3w = (const float*)d_in[11];
    const float* nn3b = (const float*)d_in[12];
    const float* lin3 = (const float*)d_in[13];
    const float* b3   = (const float*)d_in[14];

    float* ws = (float*)d_ws;
    x1_k<<<145, 512, 0, stream>>>(ws, x, ea, ei, nn1w, nn1b, lin1, b1);
    x2_k<<<NN * 16, 512, 0, stream>>>(ws, ea, ei, nn2w, nn2b, lin2, b2);
    p3_k<<<NN * 8, 512, 0, stream>>>(ws, ea, ei, nn3w, nn3b);
    x3_k<<<NN, 256, 0, stream>>>(ws, lin3, b3);
    cbt_k<<<NN, 512, 0, stream>>>(ws, (float*)d_out);
}